// Round 2
// baseline (217.150 us; speedup 1.0000x reference)
//
#include <hip/hip_runtime.h>
#include <hip/hip_bf16.h>
#include <stdint.h>

typedef __attribute__((ext_vector_type(8))) short short8;
typedef __attribute__((ext_vector_type(4))) float floatx4;

#define M_TOT 8192
#define N_TOT 3072
#define K_TOT 1024
#define BM 128
#define BN 128
#define BK 64

__device__ inline unsigned short f2bf(float f) {
    union { float f; unsigned int ui; } v; v.f = f;
    unsigned int x = v.ui;
    unsigned int r = (x + 0x7fffu + ((x >> 16) & 1u)) >> 16; // RNE
    return (unsigned short)r;
}

__device__ inline void gl2lds16(const void* g, void* l) {
    __builtin_amdgcn_global_load_lds(
        (__attribute__((address_space(1))) void*)g,
        (__attribute__((address_space(3))) void*)l,
        16, 0, 0);
}

// ---------------------------------------------------------------------------
// Kernel 0: fp32 -> bf16 convert (for x). n8 = n/8.
// ---------------------------------------------------------------------------
__global__ __launch_bounds__(256) void cvt_f32_bf16_kernel(
    const float* __restrict__ in, unsigned short* __restrict__ out, int n8)
{
    int i = blockIdx.x * 256 + threadIdx.x;
    if (i >= n8) return;
    const float4* p = (const float4*)in + (size_t)i * 2;
    float4 a = p[0], b = p[1];
    short8 s;
    s[0] = (short)f2bf(a.x); s[1] = (short)f2bf(a.y);
    s[2] = (short)f2bf(a.z); s[3] = (short)f2bf(a.w);
    s[4] = (short)f2bf(b.x); s[5] = (short)f2bf(b.y);
    s[6] = (short)f2bf(b.z); s[7] = (short)f2bf(b.w);
    *(short8*)(out + (size_t)i * 8) = s;
}

// ---------------------------------------------------------------------------
// Kernel 1: filt[o, r*128+j] = sum_i W[o, r*128+i] * R_sec[r, i, j]
// fp32 inputs, bf16 output. grid (48 o-tiles of 64, 8 r-blocks), 256 thr.
// ---------------------------------------------------------------------------
__global__ __launch_bounds__(256) void rotate_w_kernel(
    const float* __restrict__ W,    // [3072,1024] fp32
    const float* __restrict__ qR,   // [8,128,128] fp32
    const float* __restrict__ kR,
    const float* __restrict__ vR,
    unsigned short* __restrict__ Fout)   // [3072,1024] bf16
{
    __shared__ float Rs[128 * 128]; // 64 KB
    __shared__ float Ws[64 * 128];  // 32 KB

    const int tid = threadIdx.x;
    const int o0 = blockIdx.x * 64;
    const int r = blockIdx.y;

    const float* R = (o0 < 1024) ? qR : (o0 < 2048) ? kR : vR;
    R += (size_t)r * 128 * 128;

    // Load R block: 16384 floats, 16 iters x 256 thr x float4
#pragma unroll
    for (int i = 0; i < 16; ++i) {
        int idx = (i * 256 + tid) * 4;
        *(float4*)(Rs + idx) = *(const float4*)(R + idx);
    }
    // Load W tile: rows o0..o0+63, cols r*128..+127 (8192 floats)
#pragma unroll
    for (int i = 0; i < 8; ++i) {
        int idx = (i * 256 + tid) * 4;
        int row = idx >> 7;
        int col = idx & 127;
        *(float4*)(Ws + idx) =
            *(const float4*)(W + (size_t)(o0 + row) * K_TOT + r * 128 + col);
    }
    __syncthreads();

    const int jg = (tid & 15) * 8;  // j base (0,8,...,120)
    const int ob = tid >> 4;        // 0..15

    float acc[4][8];
#pragma unroll
    for (int a = 0; a < 4; ++a)
#pragma unroll
        for (int b = 0; b < 8; ++b) acc[a][b] = 0.f;

    for (int i = 0; i < 128; ++i) {
        float4 r0 = *(const float4*)(Rs + i * 128 + jg);
        float4 r1 = *(const float4*)(Rs + i * 128 + jg + 4);
        float rv[8] = {r0.x, r0.y, r0.z, r0.w, r1.x, r1.y, r1.z, r1.w};
#pragma unroll
        for (int oo = 0; oo < 4; ++oo) {
            float wv = Ws[(ob + oo * 16) * 128 + i];
#pragma unroll
            for (int t = 0; t < 8; ++t) acc[oo][t] += wv * rv[t];
        }
    }

#pragma unroll
    for (int oo = 0; oo < 4; ++oo) {
        int o = o0 + ob + oo * 16;
        short8 s;
#pragma unroll
        for (int t = 0; t < 8; ++t) s[t] = (short)f2bf(acc[oo][t]);
        *(short8*)(Fout + (size_t)o * K_TOT + r * 128 + jg) = s;
    }
}

// ---------------------------------------------------------------------------
// Kernel 2: out[m, n] = sum_k X[m,k] * F[n,k] + bias[n]   (out/bias fp32)
// m97-style: 128x128 tile, BK=64, 4 waves (2x2), 4x4 16x16x32 MFMA per wave
// ---------------------------------------------------------------------------
__global__ void gemm_bt_kernel(
    const unsigned short* __restrict__ X,  // [8192,1024] bf16 (ws)
    const unsigned short* __restrict__ F,  // [3072,1024] bf16 (ws)
    const float* __restrict__ bias,        // [3072] fp32
    float* __restrict__ out)               // [8192,3072] fp32
{
    __shared__ unsigned short As[BM * BK]; // 16 KB
    __shared__ unsigned short Bs[BN * BK]; // 16 KB

    const int tid = threadIdx.x;
    const int wave = tid >> 6;
    const int lane = tid & 63;
    const int m0 = blockIdx.x * BM;
    const int n0 = blockIdx.y * BN;

    const int wm = wave >> 1; // 0..1
    const int wn = wave & 1;  // 0..1
    const int quad = lane >> 4;
    const int l15 = lane & 15;

    const int srow_lane = lane >> 3;     // 0..7
    const int scol = (lane & 7) * 8;     // bf16 elem col (16B granules)

    floatx4 acc[4][4];
#pragma unroll
    for (int a = 0; a < 4; ++a)
#pragma unroll
        for (int b = 0; b < 4; ++b) acc[a][b] = (floatx4){0.f, 0.f, 0.f, 0.f};

    for (int k0 = 0; k0 < K_TOT; k0 += BK) {
#pragma unroll
        for (int p = 0; p < 4; ++p) {
            const int rr = (wave * 4 + p) * 8 + srow_lane;
            gl2lds16(X + (size_t)(m0 + rr) * K_TOT + k0 + scol,
                     As + (wave * 4 + p) * 512 + lane * 8);
            gl2lds16(F + (size_t)(n0 + rr) * K_TOT + k0 + scol,
                     Bs + (wave * 4 + p) * 512 + lane * 8);
        }
        __syncthreads();

#pragma unroll
        for (int ks = 0; ks < 2; ++ks) {
            short8 a[4], b[4];
#pragma unroll
            for (int mi = 0; mi < 4; ++mi)
                a[mi] = *(const short8*)(As + (wm * 64 + mi * 16 + l15) * BK +
                                         ks * 32 + quad * 8);
#pragma unroll
            for (int ni = 0; ni < 4; ++ni)
                b[ni] = *(const short8*)(Bs + (wn * 64 + ni * 16 + l15) * BK +
                                         ks * 32 + quad * 8);
#pragma unroll
            for (int mi = 0; mi < 4; ++mi)
#pragma unroll
                for (int ni = 0; ni < 4; ++ni)
                    acc[mi][ni] = __builtin_amdgcn_mfma_f32_16x16x32_bf16(
                        a[mi], b[ni], acc[mi][ni], 0, 0, 0);
        }
        __syncthreads();
    }

    // Epilogue: D[row=quad*4+reg][col=lane&15] per 16x16 tile; fp32 out.
#pragma unroll
    for (int ni = 0; ni < 4; ++ni) {
        const int col = n0 + wn * 64 + ni * 16 + l15;
        const float bv = bias[col];
#pragma unroll
        for (int mi = 0; mi < 4; ++mi) {
            const int rbase = m0 + wm * 64 + mi * 16 + quad * 4;
#pragma unroll
            for (int reg = 0; reg < 4; ++reg) {
                out[(size_t)(rbase + reg) * N_TOT + col] =
                    acc[mi][ni][reg] + bv;
            }
        }
    }
}

extern "C" void kernel_launch(void* const* d_in, const int* in_sizes, int n_in,
                              void* d_out, int out_size, void* d_ws, size_t ws_size,
                              hipStream_t stream) {
    const float* attn = (const float*)d_in[0]; // [3072,1024] fp32
    const float* bias = (const float*)d_in[1]; // [3072] fp32
    const float* x    = (const float*)d_in[2]; // [4,2048,1024] fp32
    const float* qR   = (const float*)d_in[3]; // [8,128,128] fp32
    const float* kR   = (const float*)d_in[4];
    const float* vR   = (const float*)d_in[5];

    float* out = (float*)d_out; // [4,2048,3072] fp32

    // ws layout: xb [8192*1024] bf16 (16 MB) | filt [3072*1024] bf16 (6 MB)
    unsigned short* xb   = (unsigned short*)d_ws;
    unsigned short* filt = xb + (size_t)M_TOT * K_TOT;

    const int n8 = (M_TOT * K_TOT) / 8; // 1,048,576
    cvt_f32_bf16_kernel<<<n8 / 256, 256, 0, stream>>>(x, xb, n8);
    rotate_w_kernel<<<dim3(48, 8), 256, 0, stream>>>(attn, qR, kR, vR, filt);
    gemm_bt_kernel<<<dim3(M_TOT / BM, N_TOT / BN), 256, 0, stream>>>(
        xb, filt, bias, out);
}

// Round 3
// 215.530 us; speedup vs baseline: 1.0075x; 1.0075x over previous
//
#include <hip/hip_runtime.h>
#include <hip/hip_bf16.h>
#include <stdint.h>

typedef __attribute__((ext_vector_type(8))) short short8;
typedef __attribute__((ext_vector_type(4))) float floatx4;

#define M_TOT 8192
#define N_TOT 3072
#define K_TOT 1024
#define BM 128
#define BN 128
#define BK 64

__device__ inline unsigned short f2bf(float f) {
    union { float f; unsigned int ui; } v; v.f = f;
    unsigned int x = v.ui;
    unsigned int r = (x + 0x7fffu + ((x >> 16) & 1u)) >> 16; // RNE
    return (unsigned short)r;
}

__device__ inline void gl2lds16(const void* g, void* l) {
    __builtin_amdgcn_global_load_lds(
        (__attribute__((address_space(1))) void*)g,
        (__attribute__((address_space(3))) void*)l,
        16, 0, 0);
}

// ---------------------------------------------------------------------------
// Kernel 0: fp32 -> bf16 convert (for x). n8 = n/8.
// ---------------------------------------------------------------------------
__global__ __launch_bounds__(256) void cvt_f32_bf16_kernel(
    const float* __restrict__ in, unsigned short* __restrict__ out, int n8)
{
    int i = blockIdx.x * 256 + threadIdx.x;
    if (i >= n8) return;
    const float4* p = (const float4*)in + (size_t)i * 2;
    float4 a = p[0], b = p[1];
    short8 s;
    s[0] = (short)f2bf(a.x); s[1] = (short)f2bf(a.y);
    s[2] = (short)f2bf(a.z); s[3] = (short)f2bf(a.w);
    s[4] = (short)f2bf(b.x); s[5] = (short)f2bf(b.y);
    s[6] = (short)f2bf(b.z); s[7] = (short)f2bf(b.w);
    *(short8*)(out + (size_t)i * 8) = s;
}

// ---------------------------------------------------------------------------
// Kernel 1: filt[o, r*128+j] = sum_i W[o, r*128+i] * R_sec[r, i, j]
// fp32 inputs, bf16 output. grid (48 o-tiles of 64, 8 r-blocks), 256 thr.
// ---------------------------------------------------------------------------
__global__ __launch_bounds__(256) void rotate_w_kernel(
    const float* __restrict__ W,    // [3072,1024] fp32
    const float* __restrict__ qR,   // [8,128,128] fp32
    const float* __restrict__ kR,
    const float* __restrict__ vR,
    unsigned short* __restrict__ Fout)   // [3072,1024] bf16
{
    __shared__ float Rs[128 * 128]; // 64 KB
    __shared__ float Ws[64 * 128];  // 32 KB

    const int tid = threadIdx.x;
    const int o0 = blockIdx.x * 64;
    const int r = blockIdx.y;

    const float* R = (o0 < 1024) ? qR : (o0 < 2048) ? kR : vR;
    R += (size_t)r * 128 * 128;

#pragma unroll
    for (int i = 0; i < 16; ++i) {
        int idx = (i * 256 + tid) * 4;
        *(float4*)(Rs + idx) = *(const float4*)(R + idx);
    }
#pragma unroll
    for (int i = 0; i < 8; ++i) {
        int idx = (i * 256 + tid) * 4;
        int row = idx >> 7;
        int col = idx & 127;
        *(float4*)(Ws + idx) =
            *(const float4*)(W + (size_t)(o0 + row) * K_TOT + r * 128 + col);
    }
    __syncthreads();

    const int jg = (tid & 15) * 8;  // j base (0,8,...,120)
    const int ob = tid >> 4;        // 0..15

    float acc[4][8];
#pragma unroll
    for (int a = 0; a < 4; ++a)
#pragma unroll
        for (int b = 0; b < 8; ++b) acc[a][b] = 0.f;

    for (int i = 0; i < 128; ++i) {
        float4 r0 = *(const float4*)(Rs + i * 128 + jg);
        float4 r1 = *(const float4*)(Rs + i * 128 + jg + 4);
        float rv[8] = {r0.x, r0.y, r0.z, r0.w, r1.x, r1.y, r1.z, r1.w};
#pragma unroll
        for (int oo = 0; oo < 4; ++oo) {
            float wv = Ws[(ob + oo * 16) * 128 + i];
#pragma unroll
            for (int t = 0; t < 8; ++t) acc[oo][t] += wv * rv[t];
        }
    }

#pragma unroll
    for (int oo = 0; oo < 4; ++oo) {
        int o = o0 + ob + oo * 16;
        short8 s;
#pragma unroll
        for (int t = 0; t < 8; ++t) s[t] = (short)f2bf(acc[oo][t]);
        *(short8*)(Fout + (size_t)o * K_TOT + r * 128 + jg) = s;
    }
}

// ---------------------------------------------------------------------------
// Kernel 2: out[m,n] = sum_k X[m,k]*F[n,k] + bias[n]   (bias/out fp32)
// 128x128 tile, BK=64, 4 waves (2x2), 4x4 16x16x32 MFMA per wave.
// XOR-swizzled LDS: LDS[row][cg] = G[row][cg ^ (row&7)] (cg = 16B colgroup)
// -> fragment ds_read_b128 is 2-way-per-bank-group (free) instead of 16-way.
// Epilogue bounced through LDS for full-line float4 global stores (no RFO).
// ---------------------------------------------------------------------------
__global__ void gemm_bt_kernel(
    const unsigned short* __restrict__ X,  // [8192,1024] bf16 (ws)
    const unsigned short* __restrict__ F,  // [3072,1024] bf16 (ws)
    const float* __restrict__ bias,        // [3072] fp32
    float* __restrict__ out)               // [8192,3072] fp32
{
    __shared__ __align__(16) unsigned char smem[2 * BM * BK * sizeof(unsigned short)];
    unsigned short* As = (unsigned short*)smem;            // 16 KB
    unsigned short* Bs = As + BM * BK;                     // 16 KB
    float* Cs = (float*)smem;                              // 32 KB = 64x128 fp32

    const int tid = threadIdx.x;
    const int wave = tid >> 6;
    const int lane = tid & 63;
    const int m0 = blockIdx.x * BM;
    const int n0 = blockIdx.y * BN;

    const int wm = wave >> 1; // 0..1
    const int wn = wave & 1;  // 0..1
    const int quad = lane >> 4;
    const int l15 = lane & 15;

    // staging: per instr p, wave covers 8 rows (lane>>3) x 8 colgroups (lane&7)
    const int srow_lane = lane >> 3;              // 0..7  == arow & 7
    const int scg = (lane & 7) ^ srow_lane;       // swizzled global colgroup
    const int scol = scg * 8;                     // bf16 elem col of 16B group

    floatx4 acc[4][4];
#pragma unroll
    for (int a = 0; a < 4; ++a)
#pragma unroll
        for (int b = 0; b < 4; ++b) acc[a][b] = (floatx4){0.f, 0.f, 0.f, 0.f};

    for (int k0 = 0; k0 < K_TOT; k0 += BK) {
#pragma unroll
        for (int p = 0; p < 4; ++p) {
            const int rr = (wave * 4 + p) * 8 + srow_lane;
            gl2lds16(X + (size_t)(m0 + rr) * K_TOT + k0 + scol,
                     As + (wave * 4 + p) * 512 + lane * 8);
            gl2lds16(F + (size_t)(n0 + rr) * K_TOT + k0 + scol,
                     Bs + (wave * 4 + p) * 512 + lane * 8);
        }
        __syncthreads();

#pragma unroll
        for (int ks = 0; ks < 2; ++ks) {
            // swizzled colgroup for this lane's fragment rows (row&7 == l15&7)
            const int fcg = ((ks * 4 + quad) ^ (l15 & 7)) * 8;
            short8 a[4], b[4];
#pragma unroll
            for (int mi = 0; mi < 4; ++mi)
                a[mi] = *(const short8*)(As + (wm * 64 + mi * 16 + l15) * BK + fcg);
#pragma unroll
            for (int ni = 0; ni < 4; ++ni)
                b[ni] = *(const short8*)(Bs + (wn * 64 + ni * 16 + l15) * BK + fcg);
#pragma unroll
            for (int mi = 0; mi < 4; ++mi)
#pragma unroll
                for (int ni = 0; ni < 4; ++ni)
                    acc[mi][ni] = __builtin_amdgcn_mfma_f32_16x16x32_bf16(
                        a[mi], b[ni], acc[mi][ni], 0, 0, 0);
        }
        __syncthreads();
    }

    // ---- Epilogue via LDS: two 64-row halves, full-line float4 stores ----
    float bv[4];
#pragma unroll
    for (int ni = 0; ni < 4; ++ni)
        bv[ni] = bias[n0 + wn * 64 + ni * 16 + l15];

#pragma unroll
    for (int h = 0; h < 2; ++h) {
        if (wm == h) {
#pragma unroll
            for (int mi = 0; mi < 4; ++mi)
#pragma unroll
                for (int ni = 0; ni < 4; ++ni) {
                    const int col = wn * 64 + ni * 16 + l15;
#pragma unroll
                    for (int reg = 0; reg < 4; ++reg) {
                        const int row = mi * 16 + quad * 4 + reg;
                        Cs[row * 128 + col] = acc[mi][ni][reg] + bv[ni];
                    }
                }
        }
        __syncthreads();
        // 256 threads store 64 rows x 128 cols fp32: 8 rounds of float4
#pragma unroll
        for (int t = 0; t < 8; ++t) {
            const int idx = t * 256 + tid;       // 0..2047
            const int row = idx >> 5;            // 32 float4 per row
            const int c4 = (idx & 31) * 4;
            float4 v = *(const float4*)(Cs + row * 128 + c4);
            *(float4*)(out + (size_t)(m0 + h * 64 + row) * N_TOT + n0 + c4) = v;
        }
        __syncthreads();
    }
}

extern "C" void kernel_launch(void* const* d_in, const int* in_sizes, int n_in,
                              void* d_out, int out_size, void* d_ws, size_t ws_size,
                              hipStream_t stream) {
    const float* attn = (const float*)d_in[0]; // [3072,1024] fp32
    const float* bias = (const float*)d_in[1]; // [3072] fp32
    const float* x    = (const float*)d_in[2]; // [4,2048,1024] fp32
    const float* qR   = (const float*)d_in[3]; // [8,128,128] fp32
    const float* kR   = (const float*)d_in[4];
    const float* vR   = (const float*)d_in[5];

    float* out = (float*)d_out; // [4,2048,3072] fp32

    // ws layout: xb [8192*1024] bf16 (16 MB) | filt [3072*1024] bf16 (6 MB)
    unsigned short* xb   = (unsigned short*)d_ws;
    unsigned short* filt = xb + (size_t)M_TOT * K_TOT;

    const int n8 = (M_TOT * K_TOT) / 8; // 1,048,576
    cvt_f32_bf16_kernel<<<n8 / 256, 256, 0, stream>>>(x, xb, n8);
    rotate_w_kernel<<<dim3(48, 8), 256, 0, stream>>>(attn, qR, kR, vR, filt);
    gemm_bt_kernel<<<dim3(M_TOT / BM, N_TOT / BN), 256, 0, stream>>>(
        xb, filt, bias, out);
}

// Round 4
// 210.925 us; speedup vs baseline: 1.0295x; 1.0218x over previous
//
#include <hip/hip_runtime.h>
#include <hip/hip_bf16.h>
#include <stdint.h>

typedef __attribute__((ext_vector_type(8))) short short8;
typedef __attribute__((ext_vector_type(4))) float floatx4;
typedef __attribute__((ext_vector_type(16))) float floatx16;

#define M_TOT 8192
#define N_TOT 3072
#define K_TOT 1024
#define BM 128
#define BN 128
#define BK 64

__device__ inline unsigned short f2bf(float f) {
    union { float f; unsigned int ui; } v; v.f = f;
    unsigned int x = v.ui;
    unsigned int r = (x + 0x7fffu + ((x >> 16) & 1u)) >> 16; // RNE
    return (unsigned short)r;
}

__device__ inline void gl2lds16(const void* g, void* l) {
    __builtin_amdgcn_global_load_lds(
        (__attribute__((address_space(1))) void*)g,
        (__attribute__((address_space(3))) void*)l,
        16, 0, 0);
}

// ---------------------------------------------------------------------------
// Kernel 0: fp32 -> bf16 convert (for x). n8 = n/8.
// ---------------------------------------------------------------------------
__global__ __launch_bounds__(256) void cvt_f32_bf16_kernel(
    const float* __restrict__ in, unsigned short* __restrict__ out, int n8)
{
    int i = blockIdx.x * 256 + threadIdx.x;
    if (i >= n8) return;
    const float4* p = (const float4*)in + (size_t)i * 2;
    float4 a = p[0], b = p[1];
    short8 s;
    s[0] = (short)f2bf(a.x); s[1] = (short)f2bf(a.y);
    s[2] = (short)f2bf(a.z); s[3] = (short)f2bf(a.w);
    s[4] = (short)f2bf(b.x); s[5] = (short)f2bf(b.y);
    s[6] = (short)f2bf(b.z); s[7] = (short)f2bf(b.w);
    *(short8*)(out + (size_t)i * 8) = s;
}

// ---------------------------------------------------------------------------
// Kernel 1: filt[o, r*128+j] = sum_i W[o, r*128+i] * R_sec[r, i, j]
// fp32 inputs, bf16 output. grid (48 o-tiles of 64, 8 r-blocks), 256 thr.
// Ws padded to stride 132 (4-float pad): scalar Ws reads across the 4 ob
// values in a wave land on distinct banks (was same-bank 4-way).
// ---------------------------------------------------------------------------
__global__ __launch_bounds__(256) void rotate_w_kernel(
    const float* __restrict__ W,    // [3072,1024] fp32
    const float* __restrict__ qR,   // [8,128,128] fp32
    const float* __restrict__ kR,
    const float* __restrict__ vR,
    unsigned short* __restrict__ Fout)   // [3072,1024] bf16
{
    __shared__ float Rs[128 * 128]; // 64 KB
    __shared__ float Ws[64 * 132];  // 33 KB (stride-132 padded)

    const int tid = threadIdx.x;
    const int o0 = blockIdx.x * 64;
    const int r = blockIdx.y;

    const float* R = (o0 < 1024) ? qR : (o0 < 2048) ? kR : vR;
    R += (size_t)r * 128 * 128;

#pragma unroll
    for (int i = 0; i < 16; ++i) {
        int idx = (i * 256 + tid) * 4;
        *(float4*)(Rs + idx) = *(const float4*)(R + idx);
    }
#pragma unroll
    for (int i = 0; i < 8; ++i) {
        int idx = (i * 256 + tid) * 4;
        int row = idx >> 7;
        int col = idx & 127;
        *(float4*)(Ws + row * 132 + col) =
            *(const float4*)(W + (size_t)(o0 + row) * K_TOT + r * 128 + col);
    }
    __syncthreads();

    const int jg = (tid & 15) * 8;  // j base (0,8,...,120)
    const int ob = tid >> 4;        // 0..15

    float acc[4][8];
#pragma unroll
    for (int a = 0; a < 4; ++a)
#pragma unroll
        for (int b = 0; b < 8; ++b) acc[a][b] = 0.f;

    for (int i = 0; i < 128; ++i) {
        float4 r0 = *(const float4*)(Rs + i * 128 + jg);
        float4 r1 = *(const float4*)(Rs + i * 128 + jg + 4);
        float rv[8] = {r0.x, r0.y, r0.z, r0.w, r1.x, r1.y, r1.z, r1.w};
#pragma unroll
        for (int oo = 0; oo < 4; ++oo) {
            float wv = Ws[(ob + oo * 16) * 132 + i];
#pragma unroll
            for (int t = 0; t < 8; ++t) acc[oo][t] += wv * rv[t];
        }
    }

#pragma unroll
    for (int oo = 0; oo < 4; ++oo) {
        int o = o0 + ob + oo * 16;
        short8 s;
#pragma unroll
        for (int t = 0; t < 8; ++t) s[t] = (short)f2bf(acc[oo][t]);
        *(short8*)(Fout + (size_t)o * K_TOT + r * 128 + jg) = s;
    }
}

// ---------------------------------------------------------------------------
// Kernel 2: out[m,n] = sum_k X[m,k]*F[n,k] + bias[n]   (bias/out fp32)
// 128x128 tile, BK=64, 4 waves (2x2); per wave 2x2 tiles of 32x32x16 MFMA
// (fewer, fatter MFMAs: 129 vs 155 issue-cyc per BK; 2495 vs 2075 TF ceiling).
// XOR-swizzled LDS: LDS[row][cg] = G[row][cg ^ (row&7)] (cg = 16B colgroup).
// A-frag (32x32x16): A[m=lane&31][k=8*(lane>>5)+j]; C/D: col=lane&31,
// row=(reg&3)+8*(reg>>2)+4*(lane>>5)  [m74/m101-verified].
// Epilogue bounced through LDS for full-line float4 global stores (no RFO).
// ---------------------------------------------------------------------------
__global__ void gemm_bt_kernel(
    const unsigned short* __restrict__ X,  // [8192,1024] bf16 (ws)
    const unsigned short* __restrict__ F,  // [3072,1024] bf16 (ws)
    const float* __restrict__ bias,        // [3072] fp32
    float* __restrict__ out)               // [8192,3072] fp32
{
    __shared__ __align__(16) unsigned char smem[2 * BM * BK * sizeof(unsigned short)];
    unsigned short* As = (unsigned short*)smem;            // 16 KB
    unsigned short* Bs = As + BM * BK;                     // 16 KB
    float* Cs = (float*)smem;                              // 32 KB = 64x128 fp32

    const int tid = threadIdx.x;
    const int wave = tid >> 6;
    const int lane = tid & 63;
    const int m0 = blockIdx.x * BM;
    const int n0 = blockIdx.y * BN;

    const int wm = wave >> 1; // 0..1
    const int wn = wave & 1;  // 0..1
    const int l31 = lane & 31;
    const int khalf = lane >> 5;

    // staging: per instr p, wave covers 8 rows (lane>>3) x 8 colgroups (lane&7)
    const int srow_lane = lane >> 3;              // 0..7  == row & 7
    const int scg = (lane & 7) ^ srow_lane;       // swizzled global colgroup
    const int scol = scg * 8;                     // bf16 elem col of 16B group

    floatx16 acc[2][2];
#pragma unroll
    for (int a = 0; a < 2; ++a)
#pragma unroll
        for (int b = 0; b < 2; ++b)
#pragma unroll
            for (int t = 0; t < 16; ++t) acc[a][b][t] = 0.f;

    for (int k0 = 0; k0 < K_TOT; k0 += BK) {
#pragma unroll
        for (int p = 0; p < 4; ++p) {
            const int rr = (wave * 4 + p) * 8 + srow_lane;
            gl2lds16(X + (size_t)(m0 + rr) * K_TOT + k0 + scol,
                     As + (wave * 4 + p) * 512 + lane * 8);
            gl2lds16(F + (size_t)(n0 + rr) * K_TOT + k0 + scol,
                     Bs + (wave * 4 + p) * 512 + lane * 8);
        }
        __syncthreads();

#pragma unroll
        for (int ks = 0; ks < 4; ++ks) {
            // swizzled colgroup for this lane's fragment row (row&7 == l31&7)
            const int fcg = ((ks * 2 + khalf) ^ (l31 & 7)) * 8;
            short8 a[2], b[2];
#pragma unroll
            for (int mi = 0; mi < 2; ++mi)
                a[mi] = *(const short8*)(As + (wm * 64 + mi * 32 + l31) * BK + fcg);
#pragma unroll
            for (int ni = 0; ni < 2; ++ni)
                b[ni] = *(const short8*)(Bs + (wn * 64 + ni * 32 + l31) * BK + fcg);
#pragma unroll
            for (int mi = 0; mi < 2; ++mi)
#pragma unroll
                for (int ni = 0; ni < 2; ++ni)
                    acc[mi][ni] = __builtin_amdgcn_mfma_f32_32x32x16_bf16(
                        a[mi], b[ni], acc[mi][ni], 0, 0, 0);
        }
        __syncthreads();
    }

    // ---- Epilogue via LDS: two 64-row halves, full-line float4 stores ----
    float bv[2];
#pragma unroll
    for (int ni = 0; ni < 2; ++ni)
        bv[ni] = bias[n0 + wn * 64 + ni * 32 + l31];

#pragma unroll
    for (int h = 0; h < 2; ++h) {
        if (wm == h) {
#pragma unroll
            for (int mi = 0; mi < 2; ++mi)
#pragma unroll
                for (int ni = 0; ni < 2; ++ni) {
                    const int col = wn * 64 + ni * 32 + l31;
#pragma unroll
                    for (int reg = 0; reg < 16; ++reg) {
                        const int row = mi * 32 + (reg & 3) + 8 * (reg >> 2) +
                                        4 * khalf;
                        Cs[row * 128 + col] = acc[mi][ni][reg] + bv[ni];
                    }
                }
        }
        __syncthreads();
        // 256 threads store 64 rows x 128 cols fp32: 8 rounds of float4
#pragma unroll
        for (int t = 0; t < 8; ++t) {
            const int idx = t * 256 + tid;       // 0..2047
            const int row = idx >> 5;            // 32 float4 per row
            const int c4 = (idx & 31) * 4;
            float4 v = *(const float4*)(Cs + row * 128 + c4);
            *(float4*)(out + (size_t)(m0 + h * 64 + row) * N_TOT + n0 + c4) = v;
        }
        __syncthreads();
    }
}

extern "C" void kernel_launch(void* const* d_in, const int* in_sizes, int n_in,
                              void* d_out, int out_size, void* d_ws, size_t ws_size,
                              hipStream_t stream) {
    const float* attn = (const float*)d_in[0]; // [3072,1024] fp32
    const float* bias = (const float*)d_in[1]; // [3072] fp32
    const float* x    = (const float*)d_in[2]; // [4,2048,1024] fp32
    const float* qR   = (const float*)d_in[3]; // [8,128,128] fp32
    const float* kR   = (const float*)d_in[4];
    const float* vR   = (const float*)d_in[5];

    float* out = (float*)d_out; // [4,2048,3072] fp32

    // ws layout: xb [8192*1024] bf16 (16 MB) | filt [3072*1024] bf16 (6 MB)
    unsigned short* xb   = (unsigned short*)d_ws;
    unsigned short* filt = xb + (size_t)M_TOT * K_TOT;

    const int n8 = (M_TOT * K_TOT) / 8; // 1,048,576
    cvt_f32_bf16_kernel<<<n8 / 256, 256, 0, stream>>>(x, xb, n8);
    rotate_w_kernel<<<dim3(48, 8), 256, 0, stream>>>(attn, qR, kR, vR, filt);
    gemm_bt_kernel<<<dim3(M_TOT / BM, N_TOT / BN), 256, 0, stream>>>(
        xb, filt, bias, out);
}

// Round 5
// 209.571 us; speedup vs baseline: 1.0362x; 1.0065x over previous
//
#include <hip/hip_runtime.h>
#include <hip/hip_bf16.h>
#include <stdint.h>

typedef __attribute__((ext_vector_type(8))) short short8;
typedef __attribute__((ext_vector_type(4))) float floatx4;
typedef __attribute__((ext_vector_type(16))) float floatx16;

#define M_TOT 8192
#define N_TOT 3072
#define K_TOT 1024
#define BM 128
#define BN 128
#define BK 64

__device__ inline unsigned short f2bf(float f) {
    union { float f; unsigned int ui; } v; v.f = f;
    unsigned int x = v.ui;
    unsigned int r = (x + 0x7fffu + ((x >> 16) & 1u)) >> 16; // RNE
    return (unsigned short)r;
}

__device__ inline void gl2lds16(const void* g, void* l) {
    __builtin_amdgcn_global_load_lds(
        (__attribute__((address_space(1))) void*)g,
        (__attribute__((address_space(3))) void*)l,
        16, 0, 0);
}

// ---------------------------------------------------------------------------
// Kernel 0: fp32 -> bf16 convert (for x). n8 = n/8.
// ---------------------------------------------------------------------------
__global__ __launch_bounds__(256) void cvt_f32_bf16_kernel(
    const float* __restrict__ in, unsigned short* __restrict__ out, int n8)
{
    int i = blockIdx.x * 256 + threadIdx.x;
    if (i >= n8) return;
    const float4* p = (const float4*)in + (size_t)i * 2;
    float4 a = p[0], b = p[1];
    short8 s;
    s[0] = (short)f2bf(a.x); s[1] = (short)f2bf(a.y);
    s[2] = (short)f2bf(a.z); s[3] = (short)f2bf(a.w);
    s[4] = (short)f2bf(b.x); s[5] = (short)f2bf(b.y);
    s[6] = (short)f2bf(b.z); s[7] = (short)f2bf(b.w);
    *(short8*)(out + (size_t)i * 8) = s;
}

// ---------------------------------------------------------------------------
// Kernel 1: filt[o, r*128+j] = sum_i W[o, r*128+i] * R_sec[r, i, j]
// fp32 inputs, bf16 output. grid (48 o-tiles of 64, 8 r-blocks), 256 thr.
// Ws padded to stride 132 (R4 fix: removed 4-way scalar-read conflicts).
// ---------------------------------------------------------------------------
__global__ __launch_bounds__(256) void rotate_w_kernel(
    const float* __restrict__ W,    // [3072,1024] fp32
    const float* __restrict__ qR,   // [8,128,128] fp32
    const float* __restrict__ kR,
    const float* __restrict__ vR,
    unsigned short* __restrict__ Fout)   // [3072,1024] bf16
{
    __shared__ float Rs[128 * 128]; // 64 KB
    __shared__ float Ws[64 * 132];  // 33 KB (stride-132 padded)

    const int tid = threadIdx.x;
    const int o0 = blockIdx.x * 64;
    const int r = blockIdx.y;

    const float* R = (o0 < 1024) ? qR : (o0 < 2048) ? kR : vR;
    R += (size_t)r * 128 * 128;

#pragma unroll
    for (int i = 0; i < 16; ++i) {
        int idx = (i * 256 + tid) * 4;
        *(float4*)(Rs + idx) = *(const float4*)(R + idx);
    }
#pragma unroll
    for (int i = 0; i < 8; ++i) {
        int idx = (i * 256 + tid) * 4;
        int row = idx >> 7;
        int col = idx & 127;
        *(float4*)(Ws + row * 132 + col) =
            *(const float4*)(W + (size_t)(o0 + row) * K_TOT + r * 128 + col);
    }
    __syncthreads();

    const int jg = (tid & 15) * 8;  // j base (0,8,...,120)
    const int ob = tid >> 4;        // 0..15

    float acc[4][8];
#pragma unroll
    for (int a = 0; a < 4; ++a)
#pragma unroll
        for (int b = 0; b < 8; ++b) acc[a][b] = 0.f;

    for (int i = 0; i < 128; ++i) {
        float4 r0 = *(const float4*)(Rs + i * 128 + jg);
        float4 r1 = *(const float4*)(Rs + i * 128 + jg + 4);
        float rv[8] = {r0.x, r0.y, r0.z, r0.w, r1.x, r1.y, r1.z, r1.w};
#pragma unroll
        for (int oo = 0; oo < 4; ++oo) {
            float wv = Ws[(ob + oo * 16) * 132 + i];
#pragma unroll
            for (int t = 0; t < 8; ++t) acc[oo][t] += wv * rv[t];
        }
    }

#pragma unroll
    for (int oo = 0; oo < 4; ++oo) {
        int o = o0 + ob + oo * 16;
        short8 s;
#pragma unroll
        for (int t = 0; t < 8; ++t) s[t] = (short)f2bf(acc[oo][t]);
        *(short8*)(Fout + (size_t)o * K_TOT + r * 128 + jg) = s;
    }
}

// ---------------------------------------------------------------------------
// Kernel 2: out[m,n] = sum_k X[m,k]*F[n,k] + bias[n]   (bias/out fp32)
// 128x128 tile, BK=64, 4 waves (2x2); per wave 2x2 tiles of 32x32x16 MFMA.
// Latin-square LDS swizzle: LDS[row][cg] = G[row][cg ^ f(row)],
//   f(row) = (row&7) ^ 2*((row>>3)&3)
// -> fragment-read colgroups are distinct across BOTH contiguous-8 and
//    strided-8 lane groups (R4's khalf-only XOR was 4-way in strided groups).
// C/D (32x32): col=lane&31, row=(reg&3)+8*(reg>>2)+4*(lane>>5) [m74/m101].
// Epilogue bounced through LDS for full-line float4 global stores (no RFO).
// ---------------------------------------------------------------------------
__global__ void gemm_bt_kernel(
    const unsigned short* __restrict__ X,  // [8192,1024] bf16 (ws)
    const unsigned short* __restrict__ F,  // [3072,1024] bf16 (ws)
    const float* __restrict__ bias,        // [3072] fp32
    float* __restrict__ out)               // [8192,3072] fp32
{
    __shared__ __align__(16) unsigned char smem[2 * BM * BK * sizeof(unsigned short)];
    unsigned short* As = (unsigned short*)smem;            // 16 KB
    unsigned short* Bs = As + BM * BK;                     // 16 KB
    float* Cs = (float*)smem;                              // 32 KB = 64x128 fp32

    const int tid = threadIdx.x;
    const int wave = tid >> 6;
    const int lane = tid & 63;
    const int m0 = blockIdx.x * BM;
    const int n0 = blockIdx.y * BN;

    const int wm = wave >> 1; // 0..1
    const int wn = wave & 1;  // 0..1
    const int l31 = lane & 31;
    const int khalf = lane >> 5;

    // staging: per instr p, wave covers 8 rows (lane>>3) x 8 colgroups (lane&7)
    const int srow_lane = lane >> 3;              // 0..7  == row & 7

    floatx16 acc[2][2];
#pragma unroll
    for (int a = 0; a < 2; ++a)
#pragma unroll
        for (int b = 0; b < 2; ++b)
#pragma unroll
            for (int t = 0; t < 16; ++t) acc[a][b][t] = 0.f;

    // fragment-read swizzle term: f(row), row&7 = l31&7, (row>>3)&3 = (l31>>3)&3
    const int fr_read = (l31 & 7) ^ (((l31 >> 3) & 3) << 1);

    for (int k0 = 0; k0 < K_TOT; k0 += BK) {
#pragma unroll
        for (int p = 0; p < 4; ++p) {
            const int rr = (wave * 4 + p) * 8 + srow_lane;
            // f(rr) = srow_lane ^ 2*((wave*4+p)&3)
            const int scg = (lane & 7) ^ srow_lane ^ ((((wave * 4 + p) & 3)) << 1);
            const int scol = scg * 8;
            gl2lds16(X + (size_t)(m0 + rr) * K_TOT + k0 + scol,
                     As + (wave * 4 + p) * 512 + lane * 8);
            gl2lds16(F + (size_t)(n0 + rr) * K_TOT + k0 + scol,
                     Bs + (wave * 4 + p) * 512 + lane * 8);
        }
        __syncthreads();

#pragma unroll
        for (int ks = 0; ks < 4; ++ks) {
            const int fcg = ((ks * 2 + khalf) ^ fr_read) * 8;
            short8 a[2], b[2];
#pragma unroll
            for (int mi = 0; mi < 2; ++mi)
                a[mi] = *(const short8*)(As + (wm * 64 + mi * 32 + l31) * BK + fcg);
#pragma unroll
            for (int ni = 0; ni < 2; ++ni)
                b[ni] = *(const short8*)(Bs + (wn * 64 + ni * 32 + l31) * BK + fcg);
#pragma unroll
            for (int mi = 0; mi < 2; ++mi)
#pragma unroll
                for (int ni = 0; ni < 2; ++ni)
                    acc[mi][ni] = __builtin_amdgcn_mfma_f32_32x32x16_bf16(
                        a[mi], b[ni], acc[mi][ni], 0, 0, 0);
        }
        __syncthreads();
    }

    // ---- Epilogue via LDS: two 64-row halves, full-line float4 stores ----
    float bv[2];
#pragma unroll
    for (int ni = 0; ni < 2; ++ni)
        bv[ni] = bias[n0 + wn * 64 + ni * 32 + l31];

#pragma unroll
    for (int h = 0; h < 2; ++h) {
        if (wm == h) {
#pragma unroll
            for (int mi = 0; mi < 2; ++mi)
#pragma unroll
                for (int ni = 0; ni < 2; ++ni) {
                    const int col = wn * 64 + ni * 32 + l31;
#pragma unroll
                    for (int reg = 0; reg < 16; ++reg) {
                        const int row = mi * 32 + (reg & 3) + 8 * (reg >> 2) +
                                        4 * khalf;
                        Cs[row * 128 + col] = acc[mi][ni][reg] + bv[ni];
                    }
                }
        }
        __syncthreads();
        // 256 threads store 64 rows x 128 cols fp32: 8 rounds of float4
#pragma unroll
        for (int t = 0; t < 8; ++t) {
            const int idx = t * 256 + tid;       // 0..2047
            const int row = idx >> 5;            // 32 float4 per row
            const int c4 = (idx & 31) * 4;
            float4 v = *(const float4*)(Cs + row * 128 + c4);
            *(float4*)(out + (size_t)(m0 + h * 64 + row) * N_TOT + n0 + c4) = v;
        }
        __syncthreads();
    }
}

extern "C" void kernel_launch(void* const* d_in, const int* in_sizes, int n_in,
                              void* d_out, int out_size, void* d_ws, size_t ws_size,
                              hipStream_t stream) {
    const float* attn = (const float*)d_in[0]; // [3072,1024] fp32
    const float* bias = (const float*)d_in[1]; // [3072] fp32
    const float* x    = (const float*)d_in[2]; // [4,2048,1024] fp32
    const float* qR   = (const float*)d_in[3]; // [8,128,128] fp32
    const float* kR   = (const float*)d_in[4];
    const float* vR   = (const float*)d_in[5];

    float* out = (float*)d_out; // [4,2048,3072] fp32

    // ws layout: xb [8192*1024] bf16 (16 MB) | filt [3072*1024] bf16 (6 MB)
    unsigned short* xb   = (unsigned short*)d_ws;
    unsigned short* filt = xb + (size_t)M_TOT * K_TOT;

    const int n8 = (M_TOT * K_TOT) / 8; // 1,048,576
    cvt_f32_bf16_kernel<<<n8 / 256, 256, 0, stream>>>(x, xb, n8);
    rotate_w_kernel<<<dim3(48, 8), 256, 0, stream>>>(attn, qR, kR, vR, filt);
    gemm_bt_kernel<<<dim3(M_TOT / BM, N_TOT / BN), 256, 0, stream>>>(
        xb, filt, bias, out);
}